// Round 3
// baseline (612.312 us; speedup 1.0000x reference)
//
#include <hip/hip_runtime.h>
#include <hip/hip_bf16.h>
#include <stdint.h>

#define T_TOK 4096
#define E_EXP 8
#define D_DIM 1024
#define F_DIM 4096
#define K_TOP 2
#define CAPC  1024

typedef __attribute__((ext_vector_type(8))) short short8;
typedef __attribute__((ext_vector_type(4))) float f32x4;
typedef __attribute__((ext_vector_type(4))) unsigned short u16x4;

static __device__ __forceinline__ unsigned short f2bf(float f) {
  union { float f; unsigned u; } v; v.f = f;
  unsigned r = v.u + 0x7fffu + ((v.u >> 16) & 1u);
  return (unsigned short)(r >> 16);
}

static __device__ __forceinline__ void gload_lds16(const void* g, void* l) {
  __builtin_amdgcn_global_load_lds(
      (const __attribute__((address_space(1))) unsigned int*)g,
      (__attribute__((address_space(3))) unsigned int*)l, 16, 0, 0);
}

// ---------------------------------------------------------------- routing ---
__global__ void zero_int_kernel(int* p, int n) {
  int i = blockIdx.x * 256 + threadIdx.x;
  if (i < n) p[i] = 0;
}

// One block per expert, 1024 threads. Exact top-CAP selection by weight via
// 4-pass radix-select on the f32 bit pattern (monotone for positives).
// Slot ORDER within an expert is irrelevant (combine sums over C), so slots
// above-threshold are assigned by atomic; equal-to-threshold keys (rare) are
// taken lowest-token-index-first via a block scan, matching top_k stability.
__global__ __launch_bounds__(1024) void select_kernel(
    const float* __restrict__ rw,   // (T,E) route_weight (0 where unrouted)
    int* __restrict__ sel_idx,      // (E,CAP) token id or -1
    int* __restrict__ inv_cnt,      // (T)
    int* __restrict__ inv_ec,       // (T,K) e*CAP+c
    float* __restrict__ inv_w)      // (T,K)
{
  __shared__ unsigned keys[T_TOK];      // 16 KB
  __shared__ int hist[256];
  __shared__ int scan_s[1024];
  __shared__ int sh_need;
  __shared__ unsigned sh_prefix;
  __shared__ int slot_ctr;
  const int e = blockIdx.x;
  const int tid = threadIdx.x;

  // default slots to -1 (overwritten below for filled slots)
  if (tid < CAPC) sel_idx[e * CAPC + tid] = -1;
#pragma unroll
  for (int j = 0; j < 4; ++j) {
    int t = tid * 4 + j;
    float w = rw[(size_t)t * E_EXP + e];
    keys[t] = (w > 0.f) ? __float_as_uint(w) : 0u;
  }
  if (tid == 0) slot_ctr = 0;

  int need = CAPC;
  unsigned prefix = 0;
  for (int shift = 24; shift >= 0; shift -= 8) {
    __syncthreads();
    if (tid < 256) hist[tid] = 0;
    __syncthreads();
#pragma unroll
    for (int j = 0; j < 4; ++j) {
      unsigned k = keys[tid * 4 + j];
      unsigned hi = (shift == 24) ? 0u : (k >> (shift + 8));
      if (hi == prefix) atomicAdd(&hist[(k >> shift) & 255u], 1);
    }
    __syncthreads();
    if (tid == 0) {
      int cum = 0, b = 0;
      for (b = 255; b >= 0; --b) {
        cum += hist[b];
        if (cum >= need) break;
      }
      if (b < 0) b = 0;  // safety (shouldn't happen)
      sh_need = need - (cum - hist[b]);
      sh_prefix = (prefix << 8) | (unsigned)b;
    }
    __syncthreads();
    need = sh_need;
    prefix = sh_prefix;
  }
  const unsigned thr = prefix;  // take `need` keys equal to thr, all > thr
  __syncthreads();

  // phase A: keys strictly above threshold -> arbitrary slot via atomic
  int eqflag[4], myeq = 0;
#pragma unroll
  for (int j = 0; j < 4; ++j) {
    const int t = tid * 4 + j;
    const unsigned k = keys[t];
    if (k > thr) {
      int s = atomicAdd(&slot_ctr, 1);
      sel_idx[e * CAPC + s] = t;
      int p = atomicAdd(&inv_cnt[t], 1);
      inv_ec[t * K_TOP + p] = e * CAPC + s;
      inv_w[t * K_TOP + p] = __uint_as_float(k);
    }
    eqflag[j] = (thr > 0u && k == thr) ? 1 : 0;
    myeq += eqflag[j];
  }
  // phase B: equal-to-threshold, lowest index first, `need` of them
  scan_s[tid] = myeq;
  __syncthreads();
  for (int d = 1; d < 1024; d <<= 1) {
    int v = scan_s[tid];
    int add = (tid >= d) ? scan_s[tid - d] : 0;
    __syncthreads();
    scan_s[tid] = v + add;
    __syncthreads();
  }
  int r = scan_s[tid] - myeq;          // exclusive prefix of eq flags
  const int base = CAPC - need;        // == count of keys > thr
#pragma unroll
  for (int j = 0; j < 4; ++j) {
    if (eqflag[j]) {
      if (r < need) {
        const int t = tid * 4 + j;
        const int s = base + r;
        sel_idx[e * CAPC + s] = t;
        int p = atomicAdd(&inv_cnt[t], 1);
        inv_ec[t * K_TOP + p] = e * CAPC + s;
        inv_w[t * K_TOP + p] = __uint_as_float(thr);
      }
      ++r;
    }
  }
}

// ---------------------------------------------------------------- prepass ---
__global__ void convert_x_kernel(const float* __restrict__ x,
                                 unsigned short* __restrict__ xb, int n4) {
  int i = blockIdx.x * 256 + threadIdx.x;
  if (i >= n4) return;
  f32x4 v = ((const f32x4*)x)[i];
  u16x4 o = { f2bf(v.x), f2bf(v.y), f2bf(v.z), f2bf(v.w) };
  ((u16x4*)xb)[i] = o;
}

// in: (E,R,C) f32 row-major  ->  out: (E,C,R) bf16. 64x64 tiles through LDS.
__global__ __launch_bounds__(256) void transpose_bf16_kernel(
    const float* __restrict__ in, unsigned short* __restrict__ out,
    int R, int C)
{
  __shared__ unsigned short tile[64][68];  // +4 pad breaks bank conflicts
  const int e = blockIdx.z;
  const float* inp = in + (size_t)e * R * C;
  unsigned short* outp = out + (size_t)e * R * C;
  const int c0 = blockIdx.x * 64, r0 = blockIdx.y * 64;
  const int q4 = (threadIdx.x & 15) * 4;
  const int tr = threadIdx.x >> 4;  // 0..15
  for (int rr = tr; rr < 64; rr += 16) {
    f32x4 v = *(const f32x4*)(inp + (size_t)(r0 + rr) * C + c0 + q4);
    tile[rr][q4 + 0] = f2bf(v.x);
    tile[rr][q4 + 1] = f2bf(v.y);
    tile[rr][q4 + 2] = f2bf(v.z);
    tile[rr][q4 + 3] = f2bf(v.w);
  }
  __syncthreads();
  for (int cc = tr; cc < 64; cc += 16) {
    u16x4 o = { tile[q4 + 0][cc], tile[q4 + 1][cc],
                tile[q4 + 2][cc], tile[q4 + 3][cc] };
    *(u16x4*)(outp + (size_t)(c0 + cc) * R + r0 + q4) = o;
  }
}

// ------------------------------------------------------------------ GEMMs ---
// BM=BN=128, BK=64, 256 threads = 4 waves (2x2 of 64x64), 16x16x32 bf16 MFMA,
// global_load_lds width-16 staging. XOR chunk swizzle (chunk ^= row&7) makes
// ds_read_b128 fragment reads bank-conflict-free. XCD-aware block remap:
// xcd = lin&7 owns whole expert groups; 8 co-resident blocks share a B-tile.

__global__ __launch_bounds__(256, 3) void gemm1_kernel(
    const unsigned short* __restrict__ xb,     // (T,D) bf16
    const int* __restrict__ sel_idx,           // (E,CAP)
    const unsigned short* __restrict__ w1t,    // (E,F,D) bf16
    const float* __restrict__ b1,              // (E,F)
    unsigned short* __restrict__ H)            // (E,CAP,F) bf16
{
  // grid flat: 32 x 8 x 8 = 2048. xcd = lin&7 -> expert; slot>>3 -> x (B tile),
  // slot&7 -> y, so 8 consecutive co-resident blocks share one w1t B-tile.
  const int lin = blockIdx.x + 32 * (blockIdx.y + 8 * blockIdx.z);
  const int e = lin & 7;
  const int slot = lin >> 3;           // 0..255
  const int xb_ = slot >> 3;           // 0..31
  const int yb_ = slot & 7;            // 0..7
  const int m0 = yb_ * 128;
  const int n0 = xb_ * 128;

  __shared__ __align__(16) unsigned short Asm[128 * 64];
  __shared__ __align__(16) unsigned short Bsm[128 * 64];
  const int tid = threadIdx.x;
  const int lane = tid & 63, wv = tid >> 6;
  const int wm = (wv >> 1) * 64, wn = (wv & 1) * 64;
  const int lrow = lane & 15, quad = lane >> 4;

  const int rbase = tid >> 3, seg = tid & 7;
  const int cs = seg ^ (rbase & 7);
  const unsigned short* gA[4];
  const unsigned short* gB[4];
  char* lA[4];
  char* lB[4];
  const unsigned short* w1e = w1t + (size_t)e * F_DIM * D_DIM;
#pragma unroll
  for (int it = 0; it < 4; ++it) {
    const int row = rbase + it * 32;
    int t = sel_idx[e * CAPC + m0 + row];
    if (t < 0) t = 0;
    gA[it] = xb + (size_t)t * D_DIM + cs * 8;
    gB[it] = w1e + (size_t)(n0 + row) * D_DIM + cs * 8;
    lA[it] = (char*)Asm + it * 4096 + wv * 1024;
    lB[it] = (char*)Bsm + it * 4096 + wv * 1024;
  }

  f32x4 acc[4][4];
#pragma unroll
  for (int a = 0; a < 4; ++a)
#pragma unroll
    for (int b = 0; b < 4; ++b) acc[a][b] = (f32x4){0.f, 0.f, 0.f, 0.f};

  const int sw = lrow & 7;
  for (int k0 = 0; k0 < D_DIM; k0 += 64) {
#pragma unroll
    for (int it = 0; it < 4; ++it) { gload_lds16(gA[it], lA[it]); gA[it] += 64; }
#pragma unroll
    for (int it = 0; it < 4; ++it) { gload_lds16(gB[it], lB[it]); gB[it] += 64; }
    __syncthreads();
#pragma unroll
    for (int h = 0; h < 2; ++h) {
      short8 af[4], bf[4];
#pragma unroll
      for (int mt = 0; mt < 4; ++mt)
        af[mt] = *(const short8*)(Asm + (wm + mt * 16 + lrow) * 64 +
                                  (((h << 2) + quad) ^ sw) * 8);
#pragma unroll
      for (int nt = 0; nt < 4; ++nt)
        bf[nt] = *(const short8*)(Bsm + (wn + nt * 16 + lrow) * 64 +
                                  (((h << 2) + quad) ^ sw) * 8);
#pragma unroll
      for (int mt = 0; mt < 4; ++mt)
#pragma unroll
        for (int nt = 0; nt < 4; ++nt)
          acc[mt][nt] = __builtin_amdgcn_mfma_f32_16x16x32_bf16(
              af[mt], bf[nt], acc[mt][nt], 0, 0, 0);
    }
    __syncthreads();
  }

  const float* b1e = b1 + e * F_DIM;
#pragma unroll
  for (int nt = 0; nt < 4; ++nt) {
    const int col = n0 + wn + nt * 16 + lrow;
    const float bias = b1e[col];
#pragma unroll
    for (int mt = 0; mt < 4; ++mt) {
      const int rowb = m0 + wm + mt * 16 + quad * 4;
#pragma unroll
      for (int i = 0; i < 4; ++i) {
        float v = acc[mt][nt][i] + bias;
        float u = 0.7978845608028654f * (v + 0.044715f * v * v * v);
        float th = 1.f - 2.f / (1.f + __expf(2.f * u));  // tanh(u)
        float hv = 0.5f * v * (1.f + th);
        H[((size_t)e * CAPC + rowb + i) * F_DIM + col] = f2bf(hv);
      }
    }
  }
}

// split-K=2; partial sums to P[ks]; bias added in ks==0.
__global__ __launch_bounds__(256, 3) void gemm2_kernel(
    const unsigned short* __restrict__ H,      // (E,CAP,F) bf16
    const unsigned short* __restrict__ w2t,    // (E,D,F) bf16
    const float* __restrict__ b2,              // (E,D)
    float* __restrict__ P)                     // (2,E,CAP,D) f32 partials
{
  // grid flat: 8 x 8 x 16 = 1024. Each XCD owns two (e,ks) groups; within a
  // group, 8 consecutive co-resident blocks share one w2t B-tile.
  const int lin = blockIdx.x + 8 * (blockIdx.y + 8 * blockIdx.z);
  const int xcd = lin & 7;
  const int slot = lin >> 3;           // 0..127
  const int g = xcd * 2 + (slot >> 6); // 0..15
  const int e = g & 7;
  const int ks = g >> 3;
  const int tile = slot & 63;
  const int xb_ = tile >> 3;           // 0..7 (B tile)
  const int yb_ = tile & 7;            // 0..7
  const int m0 = yb_ * 128;
  const int n0 = xb_ * 128;
  const int kbase = ks * (F_DIM / 2);

  __shared__ __align__(16) unsigned short Asm[128 * 64];
  __shared__ __align__(16) unsigned short Bsm[128 * 64];
  const int tid = threadIdx.x;
  const int lane = tid & 63, wv = tid >> 6;
  const int wm = (wv >> 1) * 64, wn = (wv & 1) * 64;
  const int lrow = lane & 15, quad = lane >> 4;

  const int rbase = tid >> 3, seg = tid & 7;
  const int cs = seg ^ (rbase & 7);
  const unsigned short* gA[4];
  const unsigned short* gB[4];
  char* lA[4];
  char* lB[4];
  const unsigned short* He = H + (size_t)e * CAPC * F_DIM;
  const unsigned short* w2e = w2t + (size_t)e * D_DIM * F_DIM;
#pragma unroll
  for (int it = 0; it < 4; ++it) {
    const int row = rbase + it * 32;
    gA[it] = He + (size_t)(m0 + row) * F_DIM + kbase + cs * 8;
    gB[it] = w2e + (size_t)(n0 + row) * F_DIM + kbase + cs * 8;
    lA[it] = (char*)Asm + it * 4096 + wv * 1024;
    lB[it] = (char*)Bsm + it * 4096 + wv * 1024;
  }

  f32x4 acc[4][4];
#pragma unroll
  for (int a = 0; a < 4; ++a)
#pragma unroll
    for (int b = 0; b < 4; ++b) acc[a][b] = (f32x4){0.f, 0.f, 0.f, 0.f};

  const int sw = lrow & 7;
  for (int k0 = 0; k0 < F_DIM / 2; k0 += 64) {
#pragma unroll
    for (int it = 0; it < 4; ++it) { gload_lds16(gA[it], lA[it]); gA[it] += 64; }
#pragma unroll
    for (int it = 0; it < 4; ++it) { gload_lds16(gB[it], lB[it]); gB[it] += 64; }
    __syncthreads();
#pragma unroll
    for (int h = 0; h < 2; ++h) {
      short8 af[4], bf[4];
#pragma unroll
      for (int mt = 0; mt < 4; ++mt)
        af[mt] = *(const short8*)(Asm + (wm + mt * 16 + lrow) * 64 +
                                  (((h << 2) + quad) ^ sw) * 8);
#pragma unroll
      for (int nt = 0; nt < 4; ++nt)
        bf[nt] = *(const short8*)(Bsm + (wn + nt * 16 + lrow) * 64 +
                                  (((h << 2) + quad) ^ sw) * 8);
#pragma unroll
      for (int mt = 0; mt < 4; ++mt)
#pragma unroll
        for (int nt = 0; nt < 4; ++nt)
          acc[mt][nt] = __builtin_amdgcn_mfma_f32_16x16x32_bf16(
              af[mt], bf[nt], acc[mt][nt], 0, 0, 0);
    }
    __syncthreads();
  }

  const float* b2e = b2 + e * D_DIM;
  float* Pk = P + (size_t)ks * E_EXP * CAPC * D_DIM;
#pragma unroll
  for (int nt = 0; nt < 4; ++nt) {
    const int col = n0 + wn + nt * 16 + lrow;
    const float bias = (ks == 0) ? b2e[col] : 0.f;
#pragma unroll
    for (int mt = 0; mt < 4; ++mt) {
      const int rowb = m0 + wm + mt * 16 + quad * 4;
#pragma unroll
      for (int i = 0; i < 4; ++i) {
        Pk[((size_t)e * CAPC + rowb + i) * D_DIM + col] = acc[mt][nt][i] + bias;
      }
    }
  }
}

// ---------------------------------------------------------------- combine ---
__global__ __launch_bounds__(256) void combine_kernel(
    const float* __restrict__ P, const int* __restrict__ inv_cnt,
    const int* __restrict__ inv_ec, const float* __restrict__ inv_w,
    float* __restrict__ y)
{
  const int t = blockIdx.x;
  const int cnt = inv_cnt[t];
  f32x4 s = {0.f, 0.f, 0.f, 0.f};
  const int d4 = threadIdx.x;  // 256 threads x float4 = 1024 = D
  const size_t half = (size_t)E_EXP * CAPC * D_DIM;
  for (int p = 0; p < cnt; ++p) {
    const int ec = inv_ec[t * K_TOP + p];
    const float w = inv_w[t * K_TOP + p];
    f32x4 v0 = ((const f32x4*)(P + (size_t)ec * D_DIM))[d4];
    f32x4 v1 = ((const f32x4*)(P + half + (size_t)ec * D_DIM))[d4];
    s += (v0 + v1) * w;
  }
  ((f32x4*)(y + (size_t)t * D_DIM))[d4] = s;
}

// ----------------------------------------------------------------- launch ---
extern "C" void kernel_launch(void* const* d_in, const int* in_sizes, int n_in,
                              void* d_out, int out_size, void* d_ws, size_t ws_size,
                              hipStream_t stream) {
  (void)in_sizes; (void)n_in; (void)out_size; (void)ws_size;
  const float* x  = (const float*)d_in[0];
  // d_in[1] = route_mask (bool) -- unused; mask == (route_weight > 0)
  const float* rw = (const float*)d_in[2];
  const float* w1 = (const float*)d_in[3];
  const float* b1 = (const float*)d_in[4];
  const float* w2 = (const float*)d_in[5];
  const float* b2 = (const float*)d_in[6];
  float* y = (float*)d_out;

  char* ws = (char*)d_ws;
  size_t off = 0;
  auto alloc = [&](size_t bytes) {
    void* p = ws + off;
    off += (bytes + 255) & ~(size_t)255;
    return p;
  };
  unsigned short* xb  = (unsigned short*)alloc((size_t)T_TOK * D_DIM * 2);
  unsigned short* w1t = (unsigned short*)alloc((size_t)E_EXP * F_DIM * D_DIM * 2);
  unsigned short* w2t = (unsigned short*)alloc((size_t)E_EXP * D_DIM * F_DIM * 2);
  unsigned short* H   = (unsigned short*)alloc((size_t)E_EXP * CAPC * F_DIM * 2);
  float* P            = (float*)alloc((size_t)2 * E_EXP * CAPC * D_DIM * 4);
  int* sel_idx        = (int*)alloc((size_t)E_EXP * CAPC * 4);
  int* inv_cnt        = (int*)alloc((size_t)T_TOK * 4);
  int* inv_ec         = (int*)alloc((size_t)T_TOK * K_TOP * 4);
  float* inv_w        = (float*)alloc((size_t)T_TOK * K_TOP * 4);

  // routing
  zero_int_kernel<<<(T_TOK + 255) / 256, 256, 0, stream>>>(inv_cnt, T_TOK);
  select_kernel<<<E_EXP, 1024, 0, stream>>>(rw, sel_idx, inv_cnt, inv_ec, inv_w);

  // prepass: bf16 convert + weight transposes
  convert_x_kernel<<<(T_TOK * D_DIM / 4 + 255) / 256, 256, 0, stream>>>(
      x, xb, T_TOK * D_DIM / 4);
  transpose_bf16_kernel<<<dim3(F_DIM / 64, D_DIM / 64, E_EXP), 256, 0, stream>>>(
      w1, w1t, D_DIM, F_DIM);  // (E,D,F) -> (E,F,D)
  transpose_bf16_kernel<<<dim3(D_DIM / 64, F_DIM / 64, E_EXP), 256, 0, stream>>>(
      w2, w2t, F_DIM, D_DIM);  // (E,F,D) -> (E,D,F)

  // expert MLP
  gemm1_kernel<<<dim3(F_DIM / 128, CAPC / 128, E_EXP), 256, 0, stream>>>(
      xb, sel_idx, w1t, b1, H);
  gemm2_kernel<<<dim3(D_DIM / 128, CAPC / 128, E_EXP * 2), 256, 0, stream>>>(
      H, w2t, b2, P);

  // weighted combine back to token order (also zeroes dropped tokens)
  combine_kernel<<<T_TOK, 256, 0, stream>>>(P, inv_cnt, inv_ec, inv_w, y);
}

// Round 4
// 534.393 us; speedup vs baseline: 1.1458x; 1.1458x over previous
//
#include <hip/hip_runtime.h>
#include <hip/hip_bf16.h>
#include <stdint.h>

#define T_TOK 4096
#define E_EXP 8
#define D_DIM 1024
#define F_DIM 4096
#define K_TOP 2
#define CAPC  1024

typedef __attribute__((ext_vector_type(8))) short short8;
typedef __attribute__((ext_vector_type(4))) float f32x4;
typedef __attribute__((ext_vector_type(4))) unsigned short u16x4;
typedef __attribute__((ext_vector_type(8))) unsigned short u16x8;

static __device__ __forceinline__ unsigned short f2bf(float f) {
  union { float f; unsigned u; } v; v.f = f;
  unsigned r = v.u + 0x7fffu + ((v.u >> 16) & 1u);
  return (unsigned short)(r >> 16);
}

static __device__ __forceinline__ void gload_lds16(const void* g, void* l) {
  __builtin_amdgcn_global_load_lds(
      (const __attribute__((address_space(1))) unsigned int*)g,
      (__attribute__((address_space(3))) unsigned int*)l, 16, 0, 0);
}

// ---------------------------------------------------------------- helpers ---
__global__ void zero_int_kernel(int* p, int n) {
  int i = blockIdx.x * 256 + threadIdx.x;
  if (i < n) p[i] = 0;
}

// ----------------------------------------------------------------- prep -----
// ONE kernel, flat grid, 256 threads/block:
//   blocks [0,8)          : radix-select routing (one block per expert)
//   blocks [8,4104)       : x f32 -> bf16 convert
//   blocks [4104,12296)   : w1/w2 transpose+convert (128x64 tiles)
// Sub-tasks are independent; select/convert hide under the transposes.
#define PREP_SEL0   0
#define PREP_CVT0   8
#define PREP_TR0    4104
#define PREP_NBLK   12296

__global__ __launch_bounds__(256) void prep_kernel(
    const float* __restrict__ x,
    const float* __restrict__ rw,
    const float* __restrict__ w1,
    const float* __restrict__ w2,
    unsigned short* __restrict__ xb,
    unsigned short* __restrict__ w1t,   // (E,F,D) bf16
    unsigned short* __restrict__ w2t,   // (E,D,F) bf16
    int* __restrict__ sel_idx,          // (E,CAP) token id or -1
    int* __restrict__ inv_cnt,          // (T) pre-zeroed
    int* __restrict__ inv_ec,           // (T,K) e*CAP+c
    float* __restrict__ inv_w)          // (T,K)
{
  __shared__ __align__(16) char smem[18560];
  __shared__ int sh_need;
  __shared__ unsigned sh_prefix;
  __shared__ int slot_ctr;
  const int bid = blockIdx.x;
  const int tid = threadIdx.x;

  if (bid >= PREP_TR0) {
    // ---- transpose+convert: in (R,C) f32 -> out (C,R) bf16, 128r x 64c tile
    const int tb = bid - PREP_TR0;
    const float* inp; unsigned short* outp; int R, C, r0, c0;
    if (tb < 4096) {            // w1: (E,1024,4096) -> (E,4096,1024)
      const int e = tb >> 9, ti = tb & 511;
      R = 1024; C = 4096;
      r0 = (ti & 7) * 128; c0 = (ti >> 3) * 64;
      inp = w1 + (size_t)e * R * C; outp = w1t + (size_t)e * R * C;
    } else {                    // w2: (E,4096,1024) -> (E,1024,4096)
      const int t2 = tb - 4096, e = t2 >> 9, ti = t2 & 511;
      R = 4096; C = 1024;
      r0 = (ti & 31) * 128; c0 = (ti >> 5) * 64;
      inp = w2 + (size_t)e * R * C; outp = w2t + (size_t)e * R * C;
    }
    unsigned short* tile = (unsigned short*)smem;  // [128][66], pad 66
    const int q4 = (tid & 15) * 4, tr = tid >> 4;
    for (int rr = tr; rr < 128; rr += 16) {
      f32x4 v = *(const f32x4*)(inp + (size_t)(r0 + rr) * C + c0 + q4);
      unsigned* t32 = (unsigned*)(tile + rr * 66 + q4);  // idx even: aligned
      t32[0] = (unsigned)f2bf(v.x) | ((unsigned)f2bf(v.y) << 16);
      t32[1] = (unsigned)f2bf(v.z) | ((unsigned)f2bf(v.w) << 16);
    }
    __syncthreads();
    const int l = tid & 15, ccb = tid >> 4;
#pragma unroll
    for (int it = 0; it < 4; ++it) {
      const int cc = ccb + it * 16;
      u16x8 o;
#pragma unroll
      for (int j = 0; j < 8; ++j) o[j] = tile[(l * 8 + j) * 66 + cc];
      *(u16x8*)(outp + (size_t)(c0 + cc) * R + r0 + l * 8) = o;
    }
    return;
  }

  if (bid >= PREP_CVT0) {
    // ---- x f32 -> bf16
    const int i = (bid - PREP_CVT0) * 256 + tid;   // < T*D/4 exactly
    f32x4 v = ((const f32x4*)x)[i];
    u16x4 o = { f2bf(v.x), f2bf(v.y), f2bf(v.z), f2bf(v.w) };
    ((u16x4*)xb)[i] = o;
    return;
  }

  // ---- radix-select routing, one block per expert, 256 threads x 16 keys.
  // Exact top-CAP by weight; slot order arbitrary (combine sums over C);
  // equal-to-threshold keys taken lowest-token-index-first (top_k stability).
  unsigned* keys = (unsigned*)smem;                 // 16 KB
  int* hist = (int*)(smem + 16384);                 // 1 KB
  int* scn  = (int*)(smem + 16384 + 1024);          // 1 KB
  const int e = bid;
  for (int c = tid; c < CAPC; c += 256) sel_idx[e * CAPC + c] = -1;
#pragma unroll
  for (int j = 0; j < 16; ++j) {
    const int t = tid * 16 + j;
    const float w = rw[(size_t)t * E_EXP + e];
    keys[t] = (w > 0.f) ? __float_as_uint(w) : 0u;
  }
  if (tid == 0) slot_ctr = 0;

  int need = CAPC;
  unsigned prefix = 0;
  for (int shift = 24; shift >= 0; shift -= 8) {
    __syncthreads();
    hist[tid] = 0;
    __syncthreads();
#pragma unroll
    for (int j = 0; j < 16; ++j) {
      const unsigned k = keys[tid * 16 + j];
      const unsigned hi = (shift == 24) ? 0u : (k >> (shift + 8));
      if (hi == prefix) atomicAdd(&hist[(k >> shift) & 255u], 1);
    }
    __syncthreads();
    if (tid == 0) {
      int cum = 0, b;
      for (b = 255; b >= 0; --b) {
        cum += hist[b];
        if (cum >= need) break;
      }
      if (b < 0) b = 0;
      sh_need = need - (cum - hist[b]);
      sh_prefix = (prefix << 8) | (unsigned)b;
    }
    __syncthreads();
    need = sh_need;
    prefix = sh_prefix;
  }
  const unsigned thr = prefix;
  __syncthreads();

  int eqbits = 0, myeq = 0;
#pragma unroll
  for (int j = 0; j < 16; ++j) {
    const int t = tid * 16 + j;
    const unsigned k = keys[t];
    if (k > thr) {
      const int s = atomicAdd(&slot_ctr, 1);
      sel_idx[e * CAPC + s] = t;
      const int p = atomicAdd(&inv_cnt[t], 1);
      inv_ec[t * K_TOP + p] = e * CAPC + s;
      inv_w[t * K_TOP + p] = __uint_as_float(k);
    }
    if (thr > 0u && k == thr) { eqbits |= (1 << j); ++myeq; }
  }
  scn[tid] = myeq;
  __syncthreads();
  for (int d = 1; d < 256; d <<= 1) {
    const int v = scn[tid];
    const int a = (tid >= d) ? scn[tid - d] : 0;
    __syncthreads();
    scn[tid] = v + a;
    __syncthreads();
  }
  int r = scn[tid] - myeq;
  const int base = CAPC - need;
#pragma unroll
  for (int j = 0; j < 16; ++j) {
    if ((eqbits >> j) & 1) {
      if (r < need) {
        const int t = tid * 16 + j;
        const int s = base + r;
        sel_idx[e * CAPC + s] = t;
        const int p = atomicAdd(&inv_cnt[t], 1);
        inv_ec[t * K_TOP + p] = e * CAPC + s;
        inv_w[t * K_TOP + p] = __uint_as_float(thr);
      }
      ++r;
    }
  }
}

// ------------------------------------------------------------------ GEMMs ---
// BM=BN=128, BK=64, 256 threads = 4 waves (2x2 of 64x64), 16x16x32 bf16 MFMA,
// global_load_lds width-16 staging. XOR chunk swizzle (chunk ^= row&7) makes
// ds_read_b128 fragment reads bank-conflict-free. Identity block mapping
// (the R3 XCD remap regressed: L2 same-line contention, everything is L3-hot).

__global__ __launch_bounds__(256, 3) void gemm1_kernel(
    const unsigned short* __restrict__ xb,     // (T,D) bf16
    const int* __restrict__ sel_idx,           // (E,CAP)
    const unsigned short* __restrict__ w1t,    // (E,F,D) bf16
    const float* __restrict__ b1,              // (E,F)
    unsigned short* __restrict__ H)            // (E,CAP,F) bf16
{
  __shared__ __align__(16) unsigned short Asm[128 * 64];
  __shared__ __align__(16) unsigned short Bsm[128 * 64];
  const int e = blockIdx.z;
  const int m0 = blockIdx.y * 128;
  const int n0 = blockIdx.x * 128;
  const int tid = threadIdx.x;
  const int lane = tid & 63, wv = tid >> 6;
  const int wm = (wv >> 1) * 64, wn = (wv & 1) * 64;
  const int lrow = lane & 15, quad = lane >> 4;

  const int rbase = tid >> 3, seg = tid & 7;
  const int cs = seg ^ (rbase & 7);
  const unsigned short* gA[4];
  const unsigned short* gB[4];
  char* lA[4];
  char* lB[4];
  const unsigned short* w1e = w1t + (size_t)e * F_DIM * D_DIM;
#pragma unroll
  for (int it = 0; it < 4; ++it) {
    const int row = rbase + it * 32;
    int t = sel_idx[e * CAPC + m0 + row];
    if (t < 0) t = 0;
    gA[it] = xb + (size_t)t * D_DIM + cs * 8;
    gB[it] = w1e + (size_t)(n0 + row) * D_DIM + cs * 8;
    lA[it] = (char*)Asm + it * 4096 + wv * 1024;
    lB[it] = (char*)Bsm + it * 4096 + wv * 1024;
  }

  f32x4 acc[4][4];
#pragma unroll
  for (int a = 0; a < 4; ++a)
#pragma unroll
    for (int b = 0; b < 4; ++b) acc[a][b] = (f32x4){0.f, 0.f, 0.f, 0.f};

  const int sw = lrow & 7;
  for (int k0 = 0; k0 < D_DIM; k0 += 64) {
#pragma unroll
    for (int it = 0; it < 4; ++it) { gload_lds16(gA[it], lA[it]); gA[it] += 64; }
#pragma unroll
    for (int it = 0; it < 4; ++it) { gload_lds16(gB[it], lB[it]); gB[it] += 64; }
    __syncthreads();
#pragma unroll
    for (int h = 0; h < 2; ++h) {
      short8 af[4], bf[4];
#pragma unroll
      for (int mt = 0; mt < 4; ++mt)
        af[mt] = *(const short8*)(Asm + (wm + mt * 16 + lrow) * 64 +
                                  (((h << 2) + quad) ^ sw) * 8);
#pragma unroll
      for (int nt = 0; nt < 4; ++nt)
        bf[nt] = *(const short8*)(Bsm + (wn + nt * 16 + lrow) * 64 +
                                  (((h << 2) + quad) ^ sw) * 8);
#pragma unroll
      for (int mt = 0; mt < 4; ++mt)
#pragma unroll
        for (int nt = 0; nt < 4; ++nt)
          acc[mt][nt] = __builtin_amdgcn_mfma_f32_16x16x32_bf16(
              af[mt], bf[nt], acc[mt][nt], 0, 0, 0);
    }
    __syncthreads();
  }

  const float* b1e = b1 + e * F_DIM;
#pragma unroll
  for (int nt = 0; nt < 4; ++nt) {
    const int col = n0 + wn + nt * 16 + lrow;
    const float bias = b1e[col];
#pragma unroll
    for (int mt = 0; mt < 4; ++mt) {
      const int rowb = m0 + wm + mt * 16 + quad * 4;
#pragma unroll
      for (int i = 0; i < 4; ++i) {
        float v = acc[mt][nt][i] + bias;
        float u = 0.7978845608028654f * (v + 0.044715f * v * v * v);
        float th = 1.f - 2.f / (1.f + __expf(2.f * u));  // tanh(u)
        float hv = 0.5f * v * (1.f + th);
        H[((size_t)e * CAPC + rowb + i) * F_DIM + col] = f2bf(hv);
      }
    }
  }
}

// split-K=2: blockIdx.z = e + 8*ks; partial sums to P[ks]; bias in ks==0.
__global__ __launch_bounds__(256, 3) void gemm2_kernel(
    const unsigned short* __restrict__ H,      // (E,CAP,F) bf16
    const unsigned short* __restrict__ w2t,    // (E,D,F) bf16
    const float* __restrict__ b2,              // (E,D)
    float* __restrict__ P)                     // (2,E,CAP,D) f32 partials
{
  __shared__ __align__(16) unsigned short Asm[128 * 64];
  __shared__ __align__(16) unsigned short Bsm[128 * 64];
  const int e = blockIdx.z & 7;
  const int ks = blockIdx.z >> 3;
  const int m0 = blockIdx.y * 128;
  const int n0 = blockIdx.x * 128;
  const int kbase = ks * (F_DIM / 2);
  const int tid = threadIdx.x;
  const int lane = tid & 63, wv = tid >> 6;
  const int wm = (wv >> 1) * 64, wn = (wv & 1) * 64;
  const int lrow = lane & 15, quad = lane >> 4;

  const int rbase = tid >> 3, seg = tid & 7;
  const int cs = seg ^ (rbase & 7);
  const unsigned short* gA[4];
  const unsigned short* gB[4];
  char* lA[4];
  char* lB[4];
  const unsigned short* He = H + (size_t)e * CAPC * F_DIM;
  const unsigned short* w2e = w2t + (size_t)e * D_DIM * F_DIM;
#pragma unroll
  for (int it = 0; it < 4; ++it) {
    const int row = rbase + it * 32;
    gA[it] = He + (size_t)(m0 + row) * F_DIM + kbase + cs * 8;
    gB[it] = w2e + (size_t)(n0 + row) * F_DIM + kbase + cs * 8;
    lA[it] = (char*)Asm + it * 4096 + wv * 1024;
    lB[it] = (char*)Bsm + it * 4096 + wv * 1024;
  }

  f32x4 acc[4][4];
#pragma unroll
  for (int a = 0; a < 4; ++a)
#pragma unroll
    for (int b = 0; b < 4; ++b) acc[a][b] = (f32x4){0.f, 0.f, 0.f, 0.f};

  const int sw = lrow & 7;
  for (int k0 = 0; k0 < F_DIM / 2; k0 += 64) {
#pragma unroll
    for (int it = 0; it < 4; ++it) { gload_lds16(gA[it], lA[it]); gA[it] += 64; }
#pragma unroll
    for (int it = 0; it < 4; ++it) { gload_lds16(gB[it], lB[it]); gB[it] += 64; }
    __syncthreads();
#pragma unroll
    for (int h = 0; h < 2; ++h) {
      short8 af[4], bf[4];
#pragma unroll
      for (int mt = 0; mt < 4; ++mt)
        af[mt] = *(const short8*)(Asm + (wm + mt * 16 + lrow) * 64 +
                                  (((h << 2) + quad) ^ sw) * 8);
#pragma unroll
      for (int nt = 0; nt < 4; ++nt)
        bf[nt] = *(const short8*)(Bsm + (wn + nt * 16 + lrow) * 64 +
                                  (((h << 2) + quad) ^ sw) * 8);
#pragma unroll
      for (int mt = 0; mt < 4; ++mt)
#pragma unroll
        for (int nt = 0; nt < 4; ++nt)
          acc[mt][nt] = __builtin_amdgcn_mfma_f32_16x16x32_bf16(
              af[mt], bf[nt], acc[mt][nt], 0, 0, 0);
    }
    __syncthreads();
  }

  const float* b2e = b2 + e * D_DIM;
  float* Pk = P + (size_t)ks * E_EXP * CAPC * D_DIM;
#pragma unroll
  for (int nt = 0; nt < 4; ++nt) {
    const int col = n0 + wn + nt * 16 + lrow;
    const float bias = (ks == 0) ? b2e[col] : 0.f;
#pragma unroll
    for (int mt = 0; mt < 4; ++mt) {
      const int rowb = m0 + wm + mt * 16 + quad * 4;
#pragma unroll
      for (int i = 0; i < 4; ++i) {
        Pk[((size_t)e * CAPC + rowb + i) * D_DIM + col] = acc[mt][nt][i] + bias;
      }
    }
  }
}

// ---------------------------------------------------------------- combine ---
__global__ __launch_bounds__(256) void combine_kernel(
    const float* __restrict__ P, const int* __restrict__ inv_cnt,
    const int* __restrict__ inv_ec, const float* __restrict__ inv_w,
    float* __restrict__ y)
{
  const int t = blockIdx.x;
  const int cnt = inv_cnt[t];
  f32x4 s = {0.f, 0.f, 0.f, 0.f};
  const int d4 = threadIdx.x;  // 256 threads x float4 = 1024 = D
  const size_t half = (size_t)E_EXP * CAPC * D_DIM;
  for (int p = 0; p < cnt; ++p) {
    const int ec = inv_ec[t * K_TOP + p];
    const float w = inv_w[t * K_TOP + p];
    f32x4 v0 = ((const f32x4*)(P + (size_t)ec * D_DIM))[d4];
    f32x4 v1 = ((const f32x4*)(P + half + (size_t)ec * D_DIM))[d4];
    s += (v0 + v1) * w;
  }
  ((f32x4*)(y + (size_t)t * D_DIM))[d4] = s;
}

// ----------------------------------------------------------------- launch ---
extern "C" void kernel_launch(void* const* d_in, const int* in_sizes, int n_in,
                              void* d_out, int out_size, void* d_ws, size_t ws_size,
                              hipStream_t stream) {
  (void)in_sizes; (void)n_in; (void)out_size; (void)ws_size;
  const float* x  = (const float*)d_in[0];
  // d_in[1] = route_mask (bool) -- unused; mask == (route_weight > 0)
  const float* rw = (const float*)d_in[2];
  const float* w1 = (const float*)d_in[3];
  const float* b1 = (const float*)d_in[4];
  const float* w2 = (const float*)d_in[5];
  const float* b2 = (const float*)d_in[6];
  float* y = (float*)d_out;

  char* ws = (char*)d_ws;
  size_t off = 0;
  auto alloc = [&](size_t bytes) {
    void* p = ws + off;
    off += (bytes + 255) & ~(size_t)255;
    return p;
  };
  unsigned short* xb  = (unsigned short*)alloc((size_t)T_TOK * D_DIM * 2);
  unsigned short* w1t = (unsigned short*)alloc((size_t)E_EXP * F_DIM * D_DIM * 2);
  unsigned short* w2t = (unsigned short*)alloc((size_t)E_EXP * D_DIM * F_DIM * 2);
  unsigned short* H   = (unsigned short*)alloc((size_t)E_EXP * CAPC * F_DIM * 2);
  float* P            = (float*)alloc((size_t)2 * E_EXP * CAPC * D_DIM * 4);
  int* sel_idx        = (int*)alloc((size_t)E_EXP * CAPC * 4);
  int* inv_cnt        = (int*)alloc((size_t)T_TOK * 4);
  int* inv_ec         = (int*)alloc((size_t)T_TOK * K_TOP * 4);
  float* inv_w        = (float*)alloc((size_t)T_TOK * K_TOP * 4);

  // 1) zero the inverse-map counters (needed before select's atomics)
  zero_int_kernel<<<(T_TOK + 255) / 256, 256, 0, stream>>>(inv_cnt, T_TOK);

  // 2) fused prep: routing select + x convert + both weight transposes
  prep_kernel<<<PREP_NBLK, 256, 0, stream>>>(
      x, rw, w1, w2, xb, w1t, w2t, sel_idx, inv_cnt, inv_ec, inv_w);

  // 3) expert MLP
  gemm1_kernel<<<dim3(F_DIM / 128, CAPC / 128, E_EXP), 256, 0, stream>>>(
      xb, sel_idx, w1t, b1, H);
  gemm2_kernel<<<dim3(D_DIM / 128, CAPC / 128, E_EXP * 2), 256, 0, stream>>>(
      H, w2t, b2, P);

  // 4) weighted combine back to token order (also zeroes dropped tokens)
  combine_kernel<<<T_TOK, 256, 0, stream>>>(P, inv_cnt, inv_ec, inv_w, y);
}